// Round 11
// baseline (603.079 us; speedup 1.0000x reference)
//
#include <hip/hip_runtime.h>
#include <math.h>

#define I_  2049
#define J_  2048
#define K_  8
#define N_  2
#define NITER 5
#define EPSF 1e-20f
#define INVJ (1.0/2048.0)
#define CHUNK 16
#define NCHUNK 129  // ceil(2049/16)

// ---------- static device-global state ----------
__device__ float4 g_Xc[(size_t)I_*J_];      // 67 MB: Xc(I,J,M) — both m of a j in one float4
__device__ float  g_Tt[I_*16];              // T transposed: [i][n][k] (n-major, k in float4 groups)
__device__ float  g_Toldt[I_*16];           // start-of-iter snapshot, same layout
__device__ float4 g_Vt4[(size_t)J_*4];      // V transposed: [j][n][k] as 4x float4 per j
__device__ float2 g_W[I_*4];                // W[i][r][c]
__device__ float2 g_Wold[I_*4];             // iteration-start snapshot
__device__ float4 g_pnA[(size_t)NCHUNK*2*J_];   // V-update partials: num n0, [c][kg][j]
__device__ float4 g_pnB[(size_t)NCHUNK*2*J_];   // num n1
__device__ float4 g_pdA[(size_t)NCHUNK*2*J_];   // den n0
__device__ float4 g_pdB[(size_t)NCHUNK*2*J_];   // den n1

__device__ __forceinline__ float frcp(float x) { return __builtin_amdgcn_rcpf(x); }

__device__ __forceinline__ float dot44(float4 a, float4 b) {
  return fmaf(a.x, b.x, fmaf(a.y, b.y, fmaf(a.z, b.z, a.w*b.w)));
}
__device__ __forceinline__ float4 f4fma(float s, float4 v, float4 a) {
  a.x = fmaf(s, v.x, a.x); a.y = fmaf(s, v.y, a.y);
  a.z = fmaf(s, v.z, a.z); a.w = fmaf(s, v.w, a.w);
  return a;
}
__device__ __forceinline__ float4 f4add(float4 a, float4 b) {
  return make_float4(a.x+b.x, a.y+b.y, a.z+b.z, a.w+b.w);
}
__device__ __forceinline__ float4 wred4(float4 v) {
  v.x += __shfl_down(v.x,32); v.y += __shfl_down(v.y,32); v.z += __shfl_down(v.z,32); v.w += __shfl_down(v.w,32);
  v.x += __shfl_down(v.x,16); v.y += __shfl_down(v.y,16); v.z += __shfl_down(v.z,16); v.w += __shfl_down(v.w,16);
  v.x += __shfl_down(v.x, 8); v.y += __shfl_down(v.y, 8); v.z += __shfl_down(v.z, 8); v.w += __shfl_down(v.w, 8);
  v.x += __shfl_down(v.x, 4); v.y += __shfl_down(v.y, 4); v.z += __shfl_down(v.z, 4); v.w += __shfl_down(v.w, 4);
  v.x += __shfl_down(v.x, 2); v.y += __shfl_down(v.y, 2); v.z += __shfl_down(v.z, 2); v.w += __shfl_down(v.w, 2);
  v.x += __shfl_down(v.x, 1); v.y += __shfl_down(v.y, 1); v.z += __shfl_down(v.z, 1); v.w += __shfl_down(v.w, 1);
  return v;
}
#define RW(x) { x += __shfl_down(x,32); x += __shfl_down(x,16); x += __shfl_down(x,8); \
                x += __shfl_down(x,4);  x += __shfl_down(x,2);  x += __shfl_down(x,1); }

// pin a float4's COMPONENTS (scalar "+v" is supported; whole-float4 tied operands are not)
#define PIN4(q) asm volatile("" : "+v"(q.x), "+v"(q.y), "+v"(q.z), "+v"(q.w))

// ---------- double-complex helpers (per-i 2x2 solve only) ----------
struct dcx { double x, y; };
__device__ __forceinline__ dcx cmul(dcx a, dcx b) { return {a.x*b.x - a.y*b.y, a.x*b.y + a.y*b.x}; }
__device__ __forceinline__ dcx cadd(dcx a, dcx b) { return {a.x + b.x, a.y + b.y}; }
__device__ __forceinline__ dcx csub(dcx a, dcx b) { return {a.x - b.x, a.y - b.y}; }
__device__ __forceinline__ dcx cneg(dcx a) { return {-a.x, -a.y}; }
__device__ __forceinline__ dcx cdiv(dcx a, dcx b) {
  double d = b.x*b.x + b.y*b.y;
  return {(a.x*b.x + a.y*b.y)/d, (a.y*b.x - a.x*b.y)/d};
}
__device__ __forceinline__ dcx csqrt_(dcx z) {   // principal branch, numpy-compatible
  double r = hypot(z.x, z.y);
  if (r == 0.0) return {0.0, 0.0};
  double t = sqrt(0.5*(r + fabs(z.x)));
  if (z.x >= 0.0) return {t, z.y/(2.0*t)};
  return {fabs(z.y)/(2.0*t), (z.y >= 0.0) ? t : -t};
}

__device__ __forceinline__ float2 cyn(float2 w0, float2 w1, float2 x0, float2 x1) {
  float2 y;
  y.x = w0.x*x0.x - w0.y*x0.y + w1.x*x1.x - w1.y*x1.y;
  y.y = w0.x*x0.y + w0.y*x0.x + w1.x*x1.y + w1.y*x1.x;
  return y;
}

// ---------- per-i 2x2 solve (double) from 12 summed moments; writes g_W/g_Wold ----------
__device__ __forceinline__ void solve12(int i, const double* s_, float2* wout) {
  dcx Wl[2][2];
  Wl[0][0] = {g_W[(size_t)i*4+0].x, g_W[(size_t)i*4+0].y};
  Wl[0][1] = {g_W[(size_t)i*4+1].x, g_W[(size_t)i*4+1].y};
  Wl[1][0] = {g_W[(size_t)i*4+2].x, g_W[(size_t)i*4+2].y};
  Wl[1][1] = {g_W[(size_t)i*4+3].x, g_W[(size_t)i*4+3].y};
#pragma unroll
  for (int n = 0; n < N_; n++) {
    dcx D00 = {s_[6*n+0]*INVJ, s_[6*n+1]*INVJ};
    dcx D01 = {s_[6*n+2]*INVJ, s_[6*n+3]*INVJ};
    dcx D11 = {s_[6*n+4]*INVJ, s_[6*n+5]*INVJ};
    dcx WD00 = cadd(cmul(Wl[0][0], D00), cmul(Wl[0][1], D01));
    dcx WD01 = cadd(cmul(Wl[0][0], D01), cmul(Wl[0][1], D11));
    dcx WD10 = cadd(cmul(Wl[1][0], D00), cmul(Wl[1][1], D01));
    dcx WD11 = cadd(cmul(Wl[1][0], D01), cmul(Wl[1][1], D11));
    dcx det = csub(cmul(WD00, WD11), cmul(WD01, WD10));
    dcx b0, b1;
    if (n == 0) { b0 = cdiv(WD11, det);        b1 = cdiv(cneg(WD10), det); }
    else        { b0 = cdiv(cneg(WD01), det);  b1 = cdiv(WD00, det); }
    dcx nrm = cadd(cmul(cmul(b0, b0), D00), cmul(cmul(b1, b1), D11));
    dcx tcr = cmul(cmul(b0, b1), D01); tcr.x *= 2.0; tcr.y *= 2.0;
    nrm = cadd(nrm, tcr);
    dcx sq = csqrt_(nrm);
    Wl[0][n] = cdiv(b0, sq);
    Wl[1][n] = cdiv(b1, sq);
  }
  float2 o00 = make_float2((float)Wl[0][0].x, (float)Wl[0][0].y);
  float2 o01 = make_float2((float)Wl[0][1].x, (float)Wl[0][1].y);
  float2 o10 = make_float2((float)Wl[1][0].x, (float)Wl[1][0].y);
  float2 o11 = make_float2((float)Wl[1][1].x, (float)Wl[1][1].y);
  g_W[(size_t)i*4+0] = o00; g_W[(size_t)i*4+1] = o01;
  g_W[(size_t)i*4+2] = o10; g_W[(size_t)i*4+3] = o11;
  g_Wold[(size_t)i*4+0] = o00; g_Wold[(size_t)i*4+1] = o01;
  g_Wold[(size_t)i*4+2] = o10; g_Wold[(size_t)i*4+3] = o11;
  wout[0] = o00; wout[1] = o01; wout[2] = o10; wout[3] = o11;
}

// ---------- setup: Tt<-T0 (transposed), Vt<-V0 (transposed), W=Wold=eye ----------
// NOTE: grid must cover I_*K_ = 16392 (> K_*J_ = 16384): 65 blocks.
__global__ __launch_bounds__(256) void k_setup(const float* __restrict__ T0,
                                               const float* __restrict__ V0) {
  int idx = blockIdx.x*256 + threadIdx.x;
  if (idx < I_*K_) {
    int i = idx >> 3, k = idx & 7;
    float2 v = ((const float2*)T0)[idx];
    g_Tt[i*16 + k]     = v.x;   // n=0
    g_Tt[i*16 + 8 + k] = v.y;   // n=1
  }
  if (idx < K_*J_) {
    int k = idx >> 11, j = idx & (J_-1);
    float2 v = ((const float2*)V0)[idx];
    float* vtf = (float*)g_Vt4;
    vtf[j*16 + k]     = v.x;   // n=0
    vtf[j*16 + 8 + k] = v.y;   // n=1
  }
  if (idx < I_*4) {
    int r = (idx >> 1) & 1, c = idx & 1;
    float2 v = make_float2((r == c) ? 1.f : 0.f, 0.f);
    g_W[idx] = v;
    g_Wold[idx] = v;
  }
}

// ---------- transpose X(M,J,I,2) -> g_Xc(I,J,M); both m fused, float4 writes ----------
__global__ __launch_bounds__(256) void k_transpose(const float* __restrict__ X) {
  __shared__ float2 s0[32][65];   // [jj][ii], m=0
  __shared__ float2 s1[32][65];   // m=1
  int i0 = blockIdx.x*64, j0 = blockIdx.y*32;
  int lane = threadIdx.x & 63, row = threadIdx.x >> 6;
  const float2* X2 = (const float2*)X;   // (m*J + j)*I + i
  int gi = i0 + lane;
  if (gi < I_) {
    for (int jj = row; jj < 32; jj += 4) {
      s0[jj][lane] = X2[(size_t)(0*J_ + j0 + jj)*I_ + gi];
      s1[jj][lane] = X2[(size_t)(1*J_ + j0 + jj)*I_ + gi];
    }
  }
  __syncthreads();
  int jj = threadIdx.x & 31, ii0 = threadIdx.x >> 5;   // 32 lanes = 32 consecutive j (512B line)
  for (int u = 0; u < 8; u++) {
    int ii = ii0*8 + u;
    int i = i0 + ii;
    if (i < I_) {
      float2 a = s0[jj][ii], b = s1[jj][ii];
      g_Xc[(size_t)i*J_ + j0 + jj] = make_float4(a.x, a.y, b.x, b.y);
    }
  }
}

// ---------- fused per-i kernel: [D-accum + mid-block solve] (doD) + T-update ----------
// Phase 1 computes rn/rd per j-step and SAVES them in pinned quads; phase 2 reuses
// them plus the pinned xv row registers. Scalar-component asm pins prevent hipcc
// from rematerializing (VGPR=52 in round 9 proved it reloads otherwise).
__global__ __launch_bounds__(256, 2) void k_tv(int doD) {
  int i = blockIdx.x, t = threadIdx.x;
  int wv = t >> 6, lane = t & 63;
  __shared__ float redD[4][12];
  __shared__ float2 sW[4];
  __shared__ float redT[4][32];

  const float4* T4 = (const float4*)g_Tt;
  float4 tt0 = T4[i*4+0], tt1 = T4[i*4+1];   // n=0: k0-3, k4-7
  float4 tt2 = T4[i*4+2], tt3 = T4[i*4+3];   // n=1

  // ---- single Xc row load, wave-sliced mapping; pinned across the barrier ----
  size_t xb = (size_t)i*J_ + wv*512 + lane;
  float4 xv0 = g_Xc[xb+0*64], xv1 = g_Xc[xb+1*64], xv2 = g_Xc[xb+2*64], xv3 = g_Xc[xb+3*64];
  float4 xv4 = g_Xc[xb+4*64], xv5 = g_Xc[xb+5*64], xv6 = g_Xc[xb+6*64], xv7 = g_Xc[xb+7*64];

  // rn/rd saves: rq0/rq1 = rn0 steps 0-3/4-7; rq2/rq3 = rn1; dq* = frcp(rn*)
  float4 rq0, rq1, rq2, rq3, dq0, dq1, dq2, dq3;

  if (doD) {
    // ---- phase 1: D moments + rn/rd save over this wave's 512-j slice ----
    float s0=0.f,s1=0.f,s2=0.f,s3=0.f,s4=0.f,s5=0.f,s6=0.f,s7=0.f,s8=0.f,s9=0.f,s10=0.f,s11=0.f;
#define DB(U, RN0S, RN1S, RD0S, RD1S) { int j = wv*512 + U*64 + lane; \
    const float4* Vp = g_Vt4 + (size_t)j*4; \
    float4 vt0=Vp[0], vt1=Vp[1], vt2=Vp[2], vt3=Vp[3]; \
    float rn0 = dot44(tt0,vt0)+dot44(tt1,vt1); \
    float rn1 = dot44(tt2,vt2)+dot44(tt3,vt3); \
    float inv0=frcp(rn0), inv1=frcp(rn1); \
    RN0S = rn0; RN1S = rn1; RD0S = inv0; RD1S = inv1; \
    float a0=xv##U.x, b0=xv##U.y, a1=xv##U.z, b1=xv##U.w; \
    float e00r=a0*a0-b0*b0, e00i=2.f*a0*b0; \
    float e01r=a0*a1-b0*b1, e01i=a0*b1+a1*b0; \
    float e11r=a1*a1-b1*b1, e11i=2.f*a1*b1; \
    s0=fmaf(e00r,inv0,s0);  s1=fmaf(e00i,inv0,s1); \
    s2=fmaf(e01r,inv0,s2);  s3=fmaf(e01i,inv0,s3); \
    s4=fmaf(e11r,inv0,s4);  s5=fmaf(e11i,inv0,s5); \
    s6=fmaf(e00r,inv1,s6);  s7=fmaf(e00i,inv1,s7); \
    s8=fmaf(e01r,inv1,s8);  s9=fmaf(e01i,inv1,s9); \
    s10=fmaf(e11r,inv1,s10); s11=fmaf(e11i,inv1,s11); }
    DB(0, rq0.x, rq2.x, dq0.x, dq2.x)
    DB(1, rq0.y, rq2.y, dq0.y, dq2.y)
    DB(2, rq0.z, rq2.z, dq0.z, dq2.z)
    DB(3, rq0.w, rq2.w, dq0.w, dq2.w)
    DB(4, rq1.x, rq3.x, dq1.x, dq3.x)
    DB(5, rq1.y, rq3.y, dq1.y, dq3.y)
    DB(6, rq1.z, rq3.z, dq1.z, dq3.z)
    DB(7, rq1.w, rq3.w, dq1.w, dq3.w)
#undef DB
    RW(s0) RW(s1) RW(s2) RW(s3) RW(s4) RW(s5) RW(s6) RW(s7) RW(s8) RW(s9) RW(s10) RW(s11)
    if (lane == 0) {
      redD[wv][0]=s0;  redD[wv][1]=s1;  redD[wv][2]=s2;  redD[wv][3]=s3;
      redD[wv][4]=s4;  redD[wv][5]=s5;  redD[wv][6]=s6;  redD[wv][7]=s7;
      redD[wv][8]=s8;  redD[wv][9]=s9;  redD[wv][10]=s10; redD[wv][11]=s11;
    }
    __syncthreads();
    if (t == 0) {
      double s_[12];
#pragma unroll
      for (int q = 0; q < 12; q++)
        s_[q] = (double)redD[0][q] + (double)redD[1][q] + (double)redD[2][q] + (double)redD[3][q];
      float2 w[4];
      solve12(i, s_, w);
      sW[0] = w[0]; sW[1] = w[1]; sW[2] = w[2]; sW[3] = w[3];
    }
  } else {
    // ---- lite phase 1: rn/rd only (W = Wold identity pass) ----
#define LB(U, RN0S, RN1S, RD0S, RD1S) { int j = wv*512 + U*64 + lane; \
    const float4* Vp = g_Vt4 + (size_t)j*4; \
    float4 vt0=Vp[0], vt1=Vp[1], vt2=Vp[2], vt3=Vp[3]; \
    float rn0 = dot44(tt0,vt0)+dot44(tt1,vt1); \
    float rn1 = dot44(tt2,vt2)+dot44(tt3,vt3); \
    RN0S = rn0; RN1S = rn1; RD0S = frcp(rn0); RD1S = frcp(rn1); }
    LB(0, rq0.x, rq2.x, dq0.x, dq2.x)
    LB(1, rq0.y, rq2.y, dq0.y, dq2.y)
    LB(2, rq0.z, rq2.z, dq0.z, dq2.z)
    LB(3, rq0.w, rq2.w, dq0.w, dq2.w)
    LB(4, rq1.x, rq3.x, dq1.x, dq3.x)
    LB(5, rq1.y, rq3.y, dq1.y, dq3.y)
    LB(6, rq1.z, rq3.z, dq1.z, dq3.z)
    LB(7, rq1.w, rq3.w, dq1.w, dq3.w)
#undef LB
    if (t == 0) {
      sW[0] = g_Wold[(size_t)i*4+0]; sW[1] = g_Wold[(size_t)i*4+1];
      sW[2] = g_Wold[(size_t)i*4+2]; sW[3] = g_Wold[(size_t)i*4+3];
    }
  }
  // pin row + rn/rd registers so the compiler cannot rematerialize across the barrier
  PIN4(xv0); PIN4(xv1); PIN4(xv2); PIN4(xv3);
  PIN4(xv4); PIN4(xv5); PIN4(xv6); PIN4(xv7);
  PIN4(rq0); PIN4(rq1); PIN4(rq2); PIN4(rq3);
  PIN4(dq0); PIN4(dq1); PIN4(dq2); PIN4(dq3);
  __syncthreads();
  float2 w00 = sW[0], w01 = sW[1], w10 = sW[2], w11 = sW[3];

  // ---- phase 2: T update — xv + rn/rd from registers; Vt only for the FMAs ----
  float4 z = make_float4(0.f,0.f,0.f,0.f);
  float4 aN0a=z, aN0b=z, aD0a=z, aD0b=z, aN1a=z, aN1b=z, aD1a=z, aD1b=z;
#define TB(U, RN0S, RN1S, RD0S, RD1S) { int j = wv*512 + U*64 + lane; \
  const float4* Vp = g_Vt4 + (size_t)j*4; \
  float4 vt0=Vp[0], vt1=Vp[1], vt2=Vp[2], vt3=Vp[3]; \
  float rn0 = RN0S, rn1 = RN1S, rd0 = RD0S, rd1 = RD1S; \
  float2 x0=make_float2(xv##U.x,xv##U.y), x1=make_float2(xv##U.z,xv##U.w); \
  float2 y0=cyn(w00,w01,x0,x1), y1=cyn(w10,w11,x0,x1); \
  float p0=(y0.x*y0.x+y0.y*y0.y)*frcp(rn0*rn0+EPSF); \
  float p1=(y1.x*y1.x+y1.y*y1.y)*frcp(rn1*rn1+EPSF); \
  aN0a=f4fma(p0,vt0,aN0a); aN0b=f4fma(p0,vt1,aN0b); \
  aD0a=f4fma(rd0,vt0,aD0a); aD0b=f4fma(rd0,vt1,aD0b); \
  aN1a=f4fma(p1,vt2,aN1a); aN1b=f4fma(p1,vt3,aN1b); \
  aD1a=f4fma(rd1,vt2,aD1a); aD1b=f4fma(rd1,vt3,aD1b); }
  TB(0, rq0.x, rq2.x, dq0.x, dq2.x)
  TB(1, rq0.y, rq2.y, dq0.y, dq2.y)
  TB(2, rq0.z, rq2.z, dq0.z, dq2.z)
  TB(3, rq0.w, rq2.w, dq0.w, dq2.w)
  TB(4, rq1.x, rq3.x, dq1.x, dq3.x)
  TB(5, rq1.y, rq3.y, dq1.y, dq3.y)
  TB(6, rq1.z, rq3.z, dq1.z, dq3.z)
  TB(7, rq1.w, rq3.w, dq1.w, dq3.w)
#undef TB
  aN0a = wred4(aN0a); aN0b = wred4(aN0b); aD0a = wred4(aD0a); aD0b = wred4(aD0b);
  aN1a = wred4(aN1a); aN1b = wred4(aN1b); aD1a = wred4(aD1a); aD1b = wred4(aD1b);
  if (lane == 0) {
    redT[wv][0]=aN0a.x;  redT[wv][1]=aN0a.y;  redT[wv][2]=aN0a.z;  redT[wv][3]=aN0a.w;
    redT[wv][4]=aN0b.x;  redT[wv][5]=aN0b.y;  redT[wv][6]=aN0b.z;  redT[wv][7]=aN0b.w;
    redT[wv][8]=aD0a.x;  redT[wv][9]=aD0a.y;  redT[wv][10]=aD0a.z; redT[wv][11]=aD0a.w;
    redT[wv][12]=aD0b.x; redT[wv][13]=aD0b.y; redT[wv][14]=aD0b.z; redT[wv][15]=aD0b.w;
    redT[wv][16]=aN1a.x; redT[wv][17]=aN1a.y; redT[wv][18]=aN1a.z; redT[wv][19]=aN1a.w;
    redT[wv][20]=aN1b.x; redT[wv][21]=aN1b.y; redT[wv][22]=aN1b.z; redT[wv][23]=aN1b.w;
    redT[wv][24]=aD1a.x; redT[wv][25]=aD1a.y; redT[wv][26]=aD1a.z; redT[wv][27]=aD1a.w;
    redT[wv][28]=aD1b.x; redT[wv][29]=aD1b.y; redT[wv][30]=aD1b.z; redT[wv][31]=aD1b.w;
  }
  __syncthreads();
  if (t < 8) {
    int k = t;
    float n0 = redT[0][k]    + redT[1][k]    + redT[2][k]    + redT[3][k];
    float d0 = redT[0][8+k]  + redT[1][8+k]  + redT[2][8+k]  + redT[3][8+k];
    float n1 = redT[0][16+k] + redT[1][16+k] + redT[2][16+k] + redT[3][16+k];
    float d1 = redT[0][24+k] + redT[1][24+k] + redT[2][24+k] + redT[3][24+k];
    float tvx = g_Tt[i*16 + k], tvy = g_Tt[i*16 + 8 + k];
    g_Toldt[i*16 + k]     = tvx;
    g_Toldt[i*16 + 8 + k] = tvy;
    g_Tt[i*16 + k]     = tvx * sqrtf(n0/d0);
    g_Tt[i*16 + 8 + k] = tvy * sqrtf(n1/d1);
  }
}

// ---------- V partial accumulation; float4 T/Told from LDS; named accumulators ----------
__global__ __launch_bounds__(256, 2) void k_vupd2() {
  int t  = threadIdx.x;
  int j  = blockIdx.x*256 + t;
  int c  = blockIdx.y;
  int i0 = c*CHUNK;
  int ni = I_ - i0; if (ni > CHUNK) ni = CHUNK;

  __shared__ float2 sWold[CHUNK*4];
  __shared__ float4 sTold[CHUNK*4];
  __shared__ float4 sT[CHUNK*4];
  const float4* To4 = (const float4*)g_Toldt;
  const float4* Tn4 = (const float4*)g_Tt;
  if (t < CHUNK*4) {
    int g = i0*4 + t; if (g < I_*4) sWold[t] = g_Wold[g];
  } else if (t < CHUNK*8) {
    int u = t - CHUNK*4; int g = i0*4 + u; if (g < I_*4) sTold[u] = To4[g];
  } else if (t < CHUNK*12) {
    int u = t - CHUNK*8; int g = i0*4 + u; if (g < I_*4) sT[u] = Tn4[g];
  }
  __syncthreads();

  const float4* Vp = g_Vt4 + (size_t)j*4;
  float4 vt0 = Vp[0], vt1 = Vp[1], vt2 = Vp[2], vt3 = Vp[3];
  float4 z = make_float4(0.f,0.f,0.f,0.f);
  float4 aN0a=z, aN0b=z, aD0a=z, aD0b=z, aN1a=z, aN1b=z, aD1a=z, aD1b=z;

  auto body = [&](int ii, float4 xv) {
    float2 x0 = make_float2(xv.x, xv.y), x1 = make_float2(xv.z, xv.w);
    float2 w00 = sWold[ii*4+0], w01 = sWold[ii*4+1], w10 = sWold[ii*4+2], w11 = sWold[ii*4+3];
    float4 to0 = sTold[ii*4+0], to1 = sTold[ii*4+1], to2 = sTold[ii*4+2], to3 = sTold[ii*4+3];
    float rn0 = dot44(to0,vt0)+dot44(to1,vt1);
    float rn1 = dot44(to2,vt2)+dot44(to3,vt3);
    float2 y0 = cyn(w00,w01,x0,x1), y1 = cyn(w10,w11,x0,x1);
    float p0 = (y0.x*y0.x+y0.y*y0.y)*frcp(rn0*rn0+EPSF);
    float p1 = (y1.x*y1.x+y1.y*y1.y)*frcp(rn1*rn1+EPSF);
    float rd0 = frcp(rn0), rd1 = frcp(rn1);
    float4 st0 = sT[ii*4+0], st1 = sT[ii*4+1], st2 = sT[ii*4+2], st3 = sT[ii*4+3];
    aN0a = f4fma(p0,  st0, aN0a); aN0b = f4fma(p0,  st1, aN0b);
    aD0a = f4fma(rd0, st0, aD0a); aD0b = f4fma(rd0, st1, aD0b);
    aN1a = f4fma(p1,  st2, aN1a); aN1b = f4fma(p1,  st3, aN1b);
    aD1a = f4fma(rd1, st2, aD1a); aD1b = f4fma(rd1, st3, aD1b);
  };

  int ii = 0;
  for (; ii + 8 <= ni; ii += 8) {
    float4 xA = g_Xc[(size_t)(i0+ii+0)*J_ + j];
    float4 xB = g_Xc[(size_t)(i0+ii+1)*J_ + j];
    float4 xC = g_Xc[(size_t)(i0+ii+2)*J_ + j];
    float4 xD = g_Xc[(size_t)(i0+ii+3)*J_ + j];
    float4 xE = g_Xc[(size_t)(i0+ii+4)*J_ + j];
    float4 xF = g_Xc[(size_t)(i0+ii+5)*J_ + j];
    float4 xG = g_Xc[(size_t)(i0+ii+6)*J_ + j];
    float4 xH = g_Xc[(size_t)(i0+ii+7)*J_ + j];
    body(ii+0,xA); body(ii+1,xB); body(ii+2,xC); body(ii+3,xD);
    body(ii+4,xE); body(ii+5,xF); body(ii+6,xG); body(ii+7,xH);
  }
  for (; ii < ni; ii++) body(ii, g_Xc[(size_t)(i0+ii)*J_ + j]);

  size_t b2 = (size_t)c*2*J_;
  g_pnA[b2 + j] = aN0a;  g_pnA[b2 + J_ + j] = aN0b;
  g_pnB[b2 + j] = aN1a;  g_pnB[b2 + J_ + j] = aN1b;
  g_pdA[b2 + j] = aD0a;  g_pdA[b2 + J_ + j] = aD0b;
  g_pdB[b2 + j] = aD1a;  g_pdB[b2 + J_ + j] = aD1b;
}

// ---------- chunk-reduce partials + apply Vt *= sqrt(num/den); float4 wide ----------
__global__ __launch_bounds__(256) void k_vapply2() {
  int t = threadIdx.x;
  int g = blockIdx.x*16 + (t & 15);         // (kg,j) group: kg = g>>11, j = g&2047
  int slice = t >> 4;                       // 16 c-slices of 9 (16*9=144 >= 129)
  int kg = g >> 11, j = g & (J_-1);
  int c0 = slice*9, c1 = c0 + 9; if (c1 > NCHUNK) c1 = NCHUNK;
  float4 z = make_float4(0.f,0.f,0.f,0.f);
  float4 sNa=z, sNb=z, sDa=z, sDb=z;
  for (int c = c0; c < c1; c++) {
    size_t o = (size_t)c*2*J_ + (size_t)kg*J_ + j;
    sNa = f4add(sNa, g_pnA[o]); sNb = f4add(sNb, g_pnB[o]);
    sDa = f4add(sDa, g_pdA[o]); sDb = f4add(sDb, g_pdB[o]);
  }
  __shared__ float4 rNa[16][16], rNb[16][16], rDa[16][16], rDb[16][16];
  rNa[slice][t & 15] = sNa; rNb[slice][t & 15] = sNb;
  rDa[slice][t & 15] = sDa; rDb[slice][t & 15] = sDb;
  __syncthreads();
  if (t < 16) {
    float4 na = rNa[0][t], nb = rNb[0][t], da = rDa[0][t], db = rDb[0][t];
#pragma unroll
    for (int s = 1; s < 16; s++) {
      na = f4add(na, rNa[s][t]); nb = f4add(nb, rNb[s][t]);
      da = f4add(da, rDa[s][t]); db = f4add(db, rDb[s][t]);
    }
    int gg = blockIdx.x*16 + t;
    int kg2 = gg >> 11, j2 = gg & (J_-1);
    float4 v0 = g_Vt4[(size_t)j2*4 + kg2];       // n=0, k-group kg2
    float4 v1 = g_Vt4[(size_t)j2*4 + 2 + kg2];   // n=1
    v0.x *= sqrtf(na.x/da.x); v0.y *= sqrtf(na.y/da.y); v0.z *= sqrtf(na.z/da.z); v0.w *= sqrtf(na.w/da.w);
    v1.x *= sqrtf(nb.x/db.x); v1.y *= sqrtf(nb.y/db.y); v1.z *= sqrtf(nb.z/db.z); v1.w *= sqrtf(nb.w/db.w);
    g_Vt4[(size_t)j2*4 + kg2] = v0;
    g_Vt4[(size_t)j2*4 + 2 + kg2] = v1;
  }
}

// ---------- final: fused D-accum + solve + Y = W · Xc output (xv pinned) ----------
__global__ __launch_bounds__(256, 2) void k_yout(float* __restrict__ out, int cplx) {
  int i = blockIdx.x, t = threadIdx.x;
  int wv = t >> 6, lane = t & 63;
  __shared__ float redD[4][12];
  __shared__ float2 sW[4];

  const float4* T4 = (const float4*)g_Tt;
  float4 tt0 = T4[i*4+0], tt1 = T4[i*4+1], tt2 = T4[i*4+2], tt3 = T4[i*4+3];

  // single Xc row load, wave-sliced mapping; pinned for the Y phase
  size_t xb = (size_t)i*J_ + wv*512 + lane;
  float4 xv0 = g_Xc[xb+0*64], xv1 = g_Xc[xb+1*64], xv2 = g_Xc[xb+2*64], xv3 = g_Xc[xb+3*64];
  float4 xv4 = g_Xc[xb+4*64], xv5 = g_Xc[xb+5*64], xv6 = g_Xc[xb+6*64], xv7 = g_Xc[xb+7*64];

  {
    float s0=0.f,s1=0.f,s2=0.f,s3=0.f,s4=0.f,s5=0.f,s6=0.f,s7=0.f,s8=0.f,s9=0.f,s10=0.f,s11=0.f;
#define DB(U) { int j = wv*512 + U*64 + lane; \
    const float4* Vp = g_Vt4 + (size_t)j*4; \
    float4 vt0=Vp[0], vt1=Vp[1], vt2=Vp[2], vt3=Vp[3]; \
    float rn0 = dot44(tt0,vt0)+dot44(tt1,vt1); \
    float rn1 = dot44(tt2,vt2)+dot44(tt3,vt3); \
    float a0=xv##U.x, b0=xv##U.y, a1=xv##U.z, b1=xv##U.w; \
    float e00r=a0*a0-b0*b0, e00i=2.f*a0*b0; \
    float e01r=a0*a1-b0*b1, e01i=a0*b1+a1*b0; \
    float e11r=a1*a1-b1*b1, e11i=2.f*a1*b1; \
    float inv0=frcp(rn0), inv1=frcp(rn1); \
    s0=fmaf(e00r,inv0,s0);  s1=fmaf(e00i,inv0,s1); \
    s2=fmaf(e01r,inv0,s2);  s3=fmaf(e01i,inv0,s3); \
    s4=fmaf(e11r,inv0,s4);  s5=fmaf(e11i,inv0,s5); \
    s6=fmaf(e00r,inv1,s6);  s7=fmaf(e00i,inv1,s7); \
    s8=fmaf(e01r,inv1,s8);  s9=fmaf(e01i,inv1,s9); \
    s10=fmaf(e11r,inv1,s10); s11=fmaf(e11i,inv1,s11); }
    DB(0) DB(1) DB(2) DB(3) DB(4) DB(5) DB(6) DB(7)
#undef DB
    RW(s0) RW(s1) RW(s2) RW(s3) RW(s4) RW(s5) RW(s6) RW(s7) RW(s8) RW(s9) RW(s10) RW(s11)
    if (lane == 0) {
      redD[wv][0]=s0;  redD[wv][1]=s1;  redD[wv][2]=s2;  redD[wv][3]=s3;
      redD[wv][4]=s4;  redD[wv][5]=s5;  redD[wv][6]=s6;  redD[wv][7]=s7;
      redD[wv][8]=s8;  redD[wv][9]=s9;  redD[wv][10]=s10; redD[wv][11]=s11;
    }
  }
  PIN4(xv0); PIN4(xv1); PIN4(xv2); PIN4(xv3);
  PIN4(xv4); PIN4(xv5); PIN4(xv6); PIN4(xv7);
  __syncthreads();
  if (t == 0) {
    double s_[12];
#pragma unroll
    for (int q = 0; q < 12; q++)
      s_[q] = (double)redD[0][q] + (double)redD[1][q] + (double)redD[2][q] + (double)redD[3][q];
    float2 w[4];
    solve12(i, s_, w);
    sW[0] = w[0]; sW[1] = w[1]; sW[2] = w[2]; sW[3] = w[3];
  }
  __syncthreads();
  float2 w00 = sW[0], w01 = sW[1], w10 = sW[2], w11 = sW[3];
  float2* out2 = (float2*)out;
#define YB(U) { int j = wv*512 + U*64 + lane; \
  float2 x0 = make_float2(xv##U.x, xv##U.y); \
  float2 x1 = make_float2(xv##U.z, xv##U.w); \
  float2 y0 = cyn(w00, w01, x0, x1); \
  float2 y1 = cyn(w10, w11, x0, x1); \
  if (cplx) { \
    out2[((size_t)i*N_ + 0)*J_ + j] = y0; \
    out2[((size_t)i*N_ + 1)*J_ + j] = y1; \
  } else { \
    out[((size_t)i*N_ + 0)*J_ + j] = y0.x; \
    out[((size_t)i*N_ + 1)*J_ + j] = y1.x; \
  } }
  YB(0) YB(1) YB(2) YB(3) YB(4) YB(5) YB(6) YB(7)
#undef YB
}

extern "C" void kernel_launch(void* const* d_in, const int* in_sizes, int n_in,
                              void* d_out, int out_size, void* d_ws, size_t ws_size,
                              hipStream_t stream) {
  const float* X  = (const float*)d_in[0];
  const float* T0 = (const float*)d_in[1];
  const float* V0 = (const float*)d_in[2];
  (void)d_ws; (void)ws_size;

  // grid covers I_*K_ = 16392 (largest init domain) — 65 blocks
  k_setup<<<(I_*K_ + 255)/256, 256, 0, stream>>>(T0, V0);
  k_transpose<<<dim3((I_ + 63)/64, J_/32), 256, 0, stream>>>(X);

  int cplx = (out_size >= 2*I_*N_*J_) ? 1 : 0;
  for (int it = 0; it < NITER; it++) {
    // it>0: k_tv solves W(it) in-block from its own D phase (prev iter's T,V), then T-update
    k_tv<<<I_, 256, 0, stream>>>(it > 0);
    k_vupd2<<<dim3(J_/256, NCHUNK), 256, 0, stream>>>();
    k_vapply2<<<2*J_/16, 256, 0, stream>>>();
  }
  k_yout<<<I_, 256, 0, stream>>>((float*)d_out, cplx);   // fused final D + solve + Y
}

// Round 12
// 514.216 us; speedup vs baseline: 1.1728x; 1.1728x over previous
//
#include <hip/hip_runtime.h>
#include <math.h>

#define I_  2049
#define J_  2048
#define K_  8
#define N_  2
#define NITER 5
#define EPSF 1e-20f
#define INVJ (1.0/2048.0)
#define CHUNK 32
#define NCHUNK 65   // ceil(2049/32)

// ---------- static device-global state ----------
__device__ float4 g_Xc[(size_t)I_*J_];      // 67 MB: Xc(I,J,M) — both m of a j in one float4
__device__ float  g_Tt[I_*16];              // T transposed: [i][n][k] (n-major, k in float4 groups)
__device__ float  g_Toldt[I_*16];           // start-of-iter snapshot, same layout
__device__ float4 g_Vt4[(size_t)J_*4];      // V transposed: [j][n][k] as 4x float4 per j
__device__ float2 g_W[I_*4];                // W[i][r][c]
__device__ float2 g_Wold[I_*4];             // iteration-start snapshot
__device__ float4 g_pnA[(size_t)NCHUNK*2*J_];   // V-update partials: num n0, [c][kg][j]
__device__ float4 g_pnB[(size_t)NCHUNK*2*J_];   // num n1
__device__ float4 g_pdA[(size_t)NCHUNK*2*J_];   // den n0
__device__ float4 g_pdB[(size_t)NCHUNK*2*J_];   // den n1

__device__ __forceinline__ float frcp(float x) { return __builtin_amdgcn_rcpf(x); }

__device__ __forceinline__ float dot44(float4 a, float4 b) {
  return fmaf(a.x, b.x, fmaf(a.y, b.y, fmaf(a.z, b.z, a.w*b.w)));
}
__device__ __forceinline__ float4 f4fma(float s, float4 v, float4 a) {
  a.x = fmaf(s, v.x, a.x); a.y = fmaf(s, v.y, a.y);
  a.z = fmaf(s, v.z, a.z); a.w = fmaf(s, v.w, a.w);
  return a;
}
__device__ __forceinline__ float4 f4add(float4 a, float4 b) {
  return make_float4(a.x+b.x, a.y+b.y, a.z+b.z, a.w+b.w);
}
__device__ __forceinline__ float4 wred4(float4 v) {
  v.x += __shfl_down(v.x,32); v.y += __shfl_down(v.y,32); v.z += __shfl_down(v.z,32); v.w += __shfl_down(v.w,32);
  v.x += __shfl_down(v.x,16); v.y += __shfl_down(v.y,16); v.z += __shfl_down(v.z,16); v.w += __shfl_down(v.w,16);
  v.x += __shfl_down(v.x, 8); v.y += __shfl_down(v.y, 8); v.z += __shfl_down(v.z, 8); v.w += __shfl_down(v.w, 8);
  v.x += __shfl_down(v.x, 4); v.y += __shfl_down(v.y, 4); v.z += __shfl_down(v.z, 4); v.w += __shfl_down(v.w, 4);
  v.x += __shfl_down(v.x, 2); v.y += __shfl_down(v.y, 2); v.z += __shfl_down(v.z, 2); v.w += __shfl_down(v.w, 2);
  v.x += __shfl_down(v.x, 1); v.y += __shfl_down(v.y, 1); v.z += __shfl_down(v.z, 1); v.w += __shfl_down(v.w, 1);
  return v;
}
#define RW(x) { x += __shfl_down(x,32); x += __shfl_down(x,16); x += __shfl_down(x,8); \
                x += __shfl_down(x,4);  x += __shfl_down(x,2);  x += __shfl_down(x,1); }

// ---------- double-complex helpers (per-i 2x2 solve only) ----------
struct dcx { double x, y; };
__device__ __forceinline__ dcx cmul(dcx a, dcx b) { return {a.x*b.x - a.y*b.y, a.x*b.y + a.y*b.x}; }
__device__ __forceinline__ dcx cadd(dcx a, dcx b) { return {a.x + b.x, a.y + b.y}; }
__device__ __forceinline__ dcx csub(dcx a, dcx b) { return {a.x - b.x, a.y - b.y}; }
__device__ __forceinline__ dcx cneg(dcx a) { return {-a.x, -a.y}; }
__device__ __forceinline__ dcx cdiv(dcx a, dcx b) {
  double d = b.x*b.x + b.y*b.y;
  return {(a.x*b.x + a.y*b.y)/d, (a.y*b.x - a.x*b.y)/d};
}
__device__ __forceinline__ dcx csqrt_(dcx z) {   // principal branch, numpy-compatible
  double r = hypot(z.x, z.y);
  if (r == 0.0) return {0.0, 0.0};
  double t = sqrt(0.5*(r + fabs(z.x)));
  if (z.x >= 0.0) return {t, z.y/(2.0*t)};
  return {fabs(z.y)/(2.0*t), (z.y >= 0.0) ? t : -t};
}

__device__ __forceinline__ float2 cyn(float2 w0, float2 w1, float2 x0, float2 x1) {
  float2 y;
  y.x = w0.x*x0.x - w0.y*x0.y + w1.x*x1.x - w1.y*x1.y;
  y.y = w0.x*x0.y + w0.y*x0.x + w1.x*x1.y + w1.y*x1.x;
  return y;
}

// ---------- per-i 2x2 solve (double) from 12 summed moments; writes g_W/g_Wold ----------
__device__ __forceinline__ void solve12(int i, const double* s_, float2* wout) {
  dcx Wl[2][2];
  Wl[0][0] = {g_W[(size_t)i*4+0].x, g_W[(size_t)i*4+0].y};
  Wl[0][1] = {g_W[(size_t)i*4+1].x, g_W[(size_t)i*4+1].y};
  Wl[1][0] = {g_W[(size_t)i*4+2].x, g_W[(size_t)i*4+2].y};
  Wl[1][1] = {g_W[(size_t)i*4+3].x, g_W[(size_t)i*4+3].y};
#pragma unroll
  for (int n = 0; n < N_; n++) {
    dcx D00 = {s_[6*n+0]*INVJ, s_[6*n+1]*INVJ};
    dcx D01 = {s_[6*n+2]*INVJ, s_[6*n+3]*INVJ};
    dcx D11 = {s_[6*n+4]*INVJ, s_[6*n+5]*INVJ};
    dcx WD00 = cadd(cmul(Wl[0][0], D00), cmul(Wl[0][1], D01));
    dcx WD01 = cadd(cmul(Wl[0][0], D01), cmul(Wl[0][1], D11));
    dcx WD10 = cadd(cmul(Wl[1][0], D00), cmul(Wl[1][1], D01));
    dcx WD11 = cadd(cmul(Wl[1][0], D01), cmul(Wl[1][1], D11));
    dcx det = csub(cmul(WD00, WD11), cmul(WD01, WD10));
    dcx b0, b1;
    if (n == 0) { b0 = cdiv(WD11, det);        b1 = cdiv(cneg(WD10), det); }
    else        { b0 = cdiv(cneg(WD01), det);  b1 = cdiv(WD00, det); }
    dcx nrm = cadd(cmul(cmul(b0, b0), D00), cmul(cmul(b1, b1), D11));
    dcx tcr = cmul(cmul(b0, b1), D01); tcr.x *= 2.0; tcr.y *= 2.0;
    nrm = cadd(nrm, tcr);
    dcx sq = csqrt_(nrm);
    Wl[0][n] = cdiv(b0, sq);
    Wl[1][n] = cdiv(b1, sq);
  }
  float2 o00 = make_float2((float)Wl[0][0].x, (float)Wl[0][0].y);
  float2 o01 = make_float2((float)Wl[0][1].x, (float)Wl[0][1].y);
  float2 o10 = make_float2((float)Wl[1][0].x, (float)Wl[1][0].y);
  float2 o11 = make_float2((float)Wl[1][1].x, (float)Wl[1][1].y);
  g_W[(size_t)i*4+0] = o00; g_W[(size_t)i*4+1] = o01;
  g_W[(size_t)i*4+2] = o10; g_W[(size_t)i*4+3] = o11;
  g_Wold[(size_t)i*4+0] = o00; g_Wold[(size_t)i*4+1] = o01;
  g_Wold[(size_t)i*4+2] = o10; g_Wold[(size_t)i*4+3] = o11;
  wout[0] = o00; wout[1] = o01; wout[2] = o10; wout[3] = o11;
}

// ---------- setup: Tt<-T0 (transposed), Vt<-V0 (transposed), W=Wold=eye ----------
// NOTE: grid must cover I_*K_ = 16392 (> K_*J_ = 16384): 65 blocks.
__global__ __launch_bounds__(256) void k_setup(const float* __restrict__ T0,
                                               const float* __restrict__ V0) {
  int idx = blockIdx.x*256 + threadIdx.x;
  if (idx < I_*K_) {
    int i = idx >> 3, k = idx & 7;
    float2 v = ((const float2*)T0)[idx];
    g_Tt[i*16 + k]     = v.x;   // n=0
    g_Tt[i*16 + 8 + k] = v.y;   // n=1
  }
  if (idx < K_*J_) {
    int k = idx >> 11, j = idx & (J_-1);
    float2 v = ((const float2*)V0)[idx];
    float* vtf = (float*)g_Vt4;
    vtf[j*16 + k]     = v.x;   // n=0
    vtf[j*16 + 8 + k] = v.y;   // n=1
  }
  if (idx < I_*4) {
    int r = (idx >> 1) & 1, c = idx & 1;
    float2 v = make_float2((r == c) ? 1.f : 0.f, 0.f);
    g_W[idx] = v;
    g_Wold[idx] = v;
  }
}

// ---------- transpose X(M,J,I,2) -> g_Xc(I,J,M); both m fused, float4 writes ----------
__global__ __launch_bounds__(256) void k_transpose(const float* __restrict__ X) {
  __shared__ float2 s0[32][65];   // [jj][ii], m=0
  __shared__ float2 s1[32][65];   // m=1
  int i0 = blockIdx.x*64, j0 = blockIdx.y*32;
  int lane = threadIdx.x & 63, row = threadIdx.x >> 6;
  const float2* X2 = (const float2*)X;   // (m*J + j)*I + i
  int gi = i0 + lane;
  if (gi < I_) {
    for (int jj = row; jj < 32; jj += 4) {
      s0[jj][lane] = X2[(size_t)(0*J_ + j0 + jj)*I_ + gi];
      s1[jj][lane] = X2[(size_t)(1*J_ + j0 + jj)*I_ + gi];
    }
  }
  __syncthreads();
  int jj = threadIdx.x & 31, ii0 = threadIdx.x >> 5;   // 32 lanes = 32 consecutive j (512B line)
  for (int u = 0; u < 8; u++) {
    int ii = ii0*8 + u;
    int i = i0 + ii;
    if (i < I_) {
      float2 a = s0[jj][ii], b = s1[jj][ii];
      g_Xc[(size_t)i*J_ + j0 + jj] = make_float4(a.x, a.y, b.x, b.y);
    }
  }
}

// ---------- fused per-i kernel: [D-accum + mid-block solve] (doD) + T-update ----------
// The Xc row is loaded from global ONCE, staged per-thread into LDS (sXc[U][tid],
// conflict-free float4 layout), and phase 2 re-reads it from LDS (~10 cyc) instead
// of L3 (~700 cyc). Registers stay free (round-11 lesson: VGPR retention kills
// occupancy; LDS is the right storage class for the cross-barrier row).
__global__ __launch_bounds__(256, 2) void k_tv(int doD) {
  int i = blockIdx.x, t = threadIdx.x;
  int wv = t >> 6, lane = t & 63;
  __shared__ float4 sXc[8][256];   // 32 KB staged row: [step][tid]
  __shared__ float redD[4][12];
  __shared__ float2 sW[4];
  __shared__ float redT[4][32];

  const float4* T4 = (const float4*)g_Tt;
  float4 tt0 = T4[i*4+0], tt1 = T4[i*4+1];   // n=0: k0-3, k4-7
  float4 tt2 = T4[i*4+2], tt3 = T4[i*4+3];   // n=1

  // ---- single global Xc row load (wave-sliced) + LDS stage ----
  size_t xb = (size_t)i*J_ + wv*512 + lane;
  float4 xv0 = g_Xc[xb+0*64], xv1 = g_Xc[xb+1*64], xv2 = g_Xc[xb+2*64], xv3 = g_Xc[xb+3*64];
  float4 xv4 = g_Xc[xb+4*64], xv5 = g_Xc[xb+5*64], xv6 = g_Xc[xb+6*64], xv7 = g_Xc[xb+7*64];
  sXc[0][t] = xv0; sXc[1][t] = xv1; sXc[2][t] = xv2; sXc[3][t] = xv3;
  sXc[4][t] = xv4; sXc[5][t] = xv5; sXc[6][t] = xv6; sXc[7][t] = xv7;

  if (doD) {
    // ---- phase 1: D moments over this wave's 512-j slice (xv still in regs) ----
    float s0=0.f,s1=0.f,s2=0.f,s3=0.f,s4=0.f,s5=0.f,s6=0.f,s7=0.f,s8=0.f,s9=0.f,s10=0.f,s11=0.f;
#define DB(U) { int j = wv*512 + U*64 + lane; \
    const float4* Vp = g_Vt4 + (size_t)j*4; \
    float4 vt0=Vp[0], vt1=Vp[1], vt2=Vp[2], vt3=Vp[3]; \
    float rn0 = dot44(tt0,vt0)+dot44(tt1,vt1); \
    float rn1 = dot44(tt2,vt2)+dot44(tt3,vt3); \
    float a0=xv##U.x, b0=xv##U.y, a1=xv##U.z, b1=xv##U.w; \
    float e00r=a0*a0-b0*b0, e00i=2.f*a0*b0; \
    float e01r=a0*a1-b0*b1, e01i=a0*b1+a1*b0; \
    float e11r=a1*a1-b1*b1, e11i=2.f*a1*b1; \
    float inv0=frcp(rn0), inv1=frcp(rn1); \
    s0=fmaf(e00r,inv0,s0);  s1=fmaf(e00i,inv0,s1); \
    s2=fmaf(e01r,inv0,s2);  s3=fmaf(e01i,inv0,s3); \
    s4=fmaf(e11r,inv0,s4);  s5=fmaf(e11i,inv0,s5); \
    s6=fmaf(e00r,inv1,s6);  s7=fmaf(e00i,inv1,s7); \
    s8=fmaf(e01r,inv1,s8);  s9=fmaf(e01i,inv1,s9); \
    s10=fmaf(e11r,inv1,s10); s11=fmaf(e11i,inv1,s11); }
    DB(0) DB(1) DB(2) DB(3) DB(4) DB(5) DB(6) DB(7)
#undef DB
    RW(s0) RW(s1) RW(s2) RW(s3) RW(s4) RW(s5) RW(s6) RW(s7) RW(s8) RW(s9) RW(s10) RW(s11)
    if (lane == 0) {
      redD[wv][0]=s0;  redD[wv][1]=s1;  redD[wv][2]=s2;  redD[wv][3]=s3;
      redD[wv][4]=s4;  redD[wv][5]=s5;  redD[wv][6]=s6;  redD[wv][7]=s7;
      redD[wv][8]=s8;  redD[wv][9]=s9;  redD[wv][10]=s10; redD[wv][11]=s11;
    }
    __syncthreads();
    if (t == 0) {
      double s_[12];
#pragma unroll
      for (int q = 0; q < 12; q++)
        s_[q] = (double)redD[0][q] + (double)redD[1][q] + (double)redD[2][q] + (double)redD[3][q];
      float2 w[4];
      solve12(i, s_, w);
      sW[0] = w[0]; sW[1] = w[1]; sW[2] = w[2]; sW[3] = w[3];
    }
  } else {
    if (t == 0) {
      sW[0] = g_Wold[(size_t)i*4+0]; sW[1] = g_Wold[(size_t)i*4+1];
      sW[2] = g_Wold[(size_t)i*4+2]; sW[3] = g_Wold[(size_t)i*4+3];
    }
  }
  __syncthreads();
  float2 w00 = sW[0], w01 = sW[1], w10 = sW[2], w11 = sW[3];

  // ---- phase 2: T update — Xc from LDS (own slots), rn recomputed from Vt (L2) ----
  float4 z = make_float4(0.f,0.f,0.f,0.f);
  float4 aN0a=z, aN0b=z, aD0a=z, aD0b=z, aN1a=z, aN1b=z, aD1a=z, aD1b=z;
#define TB(U) { int j = wv*512 + U*64 + lane; \
  const float4* Vp = g_Vt4 + (size_t)j*4; \
  float4 vt0=Vp[0], vt1=Vp[1], vt2=Vp[2], vt3=Vp[3]; \
  float4 xl = sXc[U][t]; \
  float rn0 = dot44(tt0,vt0)+dot44(tt1,vt1); \
  float rn1 = dot44(tt2,vt2)+dot44(tt3,vt3); \
  float2 x0=make_float2(xl.x,xl.y), x1=make_float2(xl.z,xl.w); \
  float2 y0=cyn(w00,w01,x0,x1), y1=cyn(w10,w11,x0,x1); \
  float p0=(y0.x*y0.x+y0.y*y0.y)*frcp(rn0*rn0+EPSF); \
  float p1=(y1.x*y1.x+y1.y*y1.y)*frcp(rn1*rn1+EPSF); \
  float rd0=frcp(rn0), rd1=frcp(rn1); \
  aN0a=f4fma(p0,vt0,aN0a); aN0b=f4fma(p0,vt1,aN0b); \
  aD0a=f4fma(rd0,vt0,aD0a); aD0b=f4fma(rd0,vt1,aD0b); \
  aN1a=f4fma(p1,vt2,aN1a); aN1b=f4fma(p1,vt3,aN1b); \
  aD1a=f4fma(rd1,vt2,aD1a); aD1b=f4fma(rd1,vt3,aD1b); }
  TB(0) TB(1) TB(2) TB(3) TB(4) TB(5) TB(6) TB(7)
#undef TB
  aN0a = wred4(aN0a); aN0b = wred4(aN0b); aD0a = wred4(aD0a); aD0b = wred4(aD0b);
  aN1a = wred4(aN1a); aN1b = wred4(aN1b); aD1a = wred4(aD1a); aD1b = wred4(aD1b);
  if (lane == 0) {
    redT[wv][0]=aN0a.x;  redT[wv][1]=aN0a.y;  redT[wv][2]=aN0a.z;  redT[wv][3]=aN0a.w;
    redT[wv][4]=aN0b.x;  redT[wv][5]=aN0b.y;  redT[wv][6]=aN0b.z;  redT[wv][7]=aN0b.w;
    redT[wv][8]=aD0a.x;  redT[wv][9]=aD0a.y;  redT[wv][10]=aD0a.z; redT[wv][11]=aD0a.w;
    redT[wv][12]=aD0b.x; redT[wv][13]=aD0b.y; redT[wv][14]=aD0b.z; redT[wv][15]=aD0b.w;
    redT[wv][16]=aN1a.x; redT[wv][17]=aN1a.y; redT[wv][18]=aN1a.z; redT[wv][19]=aN1a.w;
    redT[wv][20]=aN1b.x; redT[wv][21]=aN1b.y; redT[wv][22]=aN1b.z; redT[wv][23]=aN1b.w;
    redT[wv][24]=aD1a.x; redT[wv][25]=aD1a.y; redT[wv][26]=aD1a.z; redT[wv][27]=aD1a.w;
    redT[wv][28]=aD1b.x; redT[wv][29]=aD1b.y; redT[wv][30]=aD1b.z; redT[wv][31]=aD1b.w;
  }
  __syncthreads();
  if (t < 8) {
    int k = t;
    float n0 = redT[0][k]    + redT[1][k]    + redT[2][k]    + redT[3][k];
    float d0 = redT[0][8+k]  + redT[1][8+k]  + redT[2][8+k]  + redT[3][8+k];
    float n1 = redT[0][16+k] + redT[1][16+k] + redT[2][16+k] + redT[3][16+k];
    float d1 = redT[0][24+k] + redT[1][24+k] + redT[2][24+k] + redT[3][24+k];
    float tvx = g_Tt[i*16 + k], tvy = g_Tt[i*16 + 8 + k];
    g_Toldt[i*16 + k]     = tvx;
    g_Toldt[i*16 + 8 + k] = tvy;
    g_Tt[i*16 + k]     = tvx * sqrtf(n0/d0);
    g_Tt[i*16 + 8 + k] = tvy * sqrtf(n1/d1);
  }
}

// ---------- V partial accumulation; CHUNK=32 halves the partial traffic ----------
__global__ __launch_bounds__(256, 2) void k_vupd2() {
  int t  = threadIdx.x;
  int j  = blockIdx.x*256 + t;
  int c  = blockIdx.y;
  int i0 = c*CHUNK;
  int ni = I_ - i0; if (ni > CHUNK) ni = CHUNK;

  __shared__ float2 sWold[CHUNK*4];
  __shared__ float4 sTold[CHUNK*4];
  __shared__ float4 sT[CHUNK*4];
  const float4* To4 = (const float4*)g_Toldt;
  const float4* Tn4 = (const float4*)g_Tt;
  for (int u = t; u < CHUNK*12; u += 256) {
    if (u < CHUNK*4) {
      int g = i0*4 + u;               if (g < I_*4) sWold[u] = g_Wold[g];
    } else if (u < CHUNK*8) {
      int v = u - CHUNK*4; int g = i0*4 + v; if (g < I_*4) sTold[v] = To4[g];
    } else {
      int v = u - CHUNK*8; int g = i0*4 + v; if (g < I_*4) sT[v] = Tn4[g];
    }
  }
  __syncthreads();

  const float4* Vp = g_Vt4 + (size_t)j*4;
  float4 vt0 = Vp[0], vt1 = Vp[1], vt2 = Vp[2], vt3 = Vp[3];
  float4 z = make_float4(0.f,0.f,0.f,0.f);
  float4 aN0a=z, aN0b=z, aD0a=z, aD0b=z, aN1a=z, aN1b=z, aD1a=z, aD1b=z;

  auto body = [&](int ii, float4 xv) {
    float2 x0 = make_float2(xv.x, xv.y), x1 = make_float2(xv.z, xv.w);
    float2 w00 = sWold[ii*4+0], w01 = sWold[ii*4+1], w10 = sWold[ii*4+2], w11 = sWold[ii*4+3];
    float4 to0 = sTold[ii*4+0], to1 = sTold[ii*4+1], to2 = sTold[ii*4+2], to3 = sTold[ii*4+3];
    float rn0 = dot44(to0,vt0)+dot44(to1,vt1);
    float rn1 = dot44(to2,vt2)+dot44(to3,vt3);
    float2 y0 = cyn(w00,w01,x0,x1), y1 = cyn(w10,w11,x0,x1);
    float p0 = (y0.x*y0.x+y0.y*y0.y)*frcp(rn0*rn0+EPSF);
    float p1 = (y1.x*y1.x+y1.y*y1.y)*frcp(rn1*rn1+EPSF);
    float rd0 = frcp(rn0), rd1 = frcp(rn1);
    float4 st0 = sT[ii*4+0], st1 = sT[ii*4+1], st2 = sT[ii*4+2], st3 = sT[ii*4+3];
    aN0a = f4fma(p0,  st0, aN0a); aN0b = f4fma(p0,  st1, aN0b);
    aD0a = f4fma(rd0, st0, aD0a); aD0b = f4fma(rd0, st1, aD0b);
    aN1a = f4fma(p1,  st2, aN1a); aN1b = f4fma(p1,  st3, aN1b);
    aD1a = f4fma(rd1, st2, aD1a); aD1b = f4fma(rd1, st3, aD1b);
  };

  int ii = 0;
  for (; ii + 8 <= ni; ii += 8) {
    float4 xA = g_Xc[(size_t)(i0+ii+0)*J_ + j];
    float4 xB = g_Xc[(size_t)(i0+ii+1)*J_ + j];
    float4 xC = g_Xc[(size_t)(i0+ii+2)*J_ + j];
    float4 xD = g_Xc[(size_t)(i0+ii+3)*J_ + j];
    float4 xE = g_Xc[(size_t)(i0+ii+4)*J_ + j];
    float4 xF = g_Xc[(size_t)(i0+ii+5)*J_ + j];
    float4 xG = g_Xc[(size_t)(i0+ii+6)*J_ + j];
    float4 xH = g_Xc[(size_t)(i0+ii+7)*J_ + j];
    body(ii+0,xA); body(ii+1,xB); body(ii+2,xC); body(ii+3,xD);
    body(ii+4,xE); body(ii+5,xF); body(ii+6,xG); body(ii+7,xH);
  }
  for (; ii < ni; ii++) body(ii, g_Xc[(size_t)(i0+ii)*J_ + j]);

  size_t b2 = (size_t)c*2*J_;
  g_pnA[b2 + j] = aN0a;  g_pnA[b2 + J_ + j] = aN0b;
  g_pnB[b2 + j] = aN1a;  g_pnB[b2 + J_ + j] = aN1b;
  g_pdA[b2 + j] = aD0a;  g_pdA[b2 + J_ + j] = aD0b;
  g_pdB[b2 + j] = aD1a;  g_pdB[b2 + J_ + j] = aD1b;
}

// ---------- chunk-reduce partials + apply Vt *= sqrt(num/den); float4 wide ----------
__global__ __launch_bounds__(256) void k_vapply2() {
  int t = threadIdx.x;
  int g = blockIdx.x*16 + (t & 15);         // (kg,j) group: kg = g>>11, j = g&2047
  int slice = t >> 4;                       // 16 c-slices of 5 (16*5=80 >= 65)
  int kg = g >> 11, j = g & (J_-1);
  int c0 = slice*5, c1 = c0 + 5; if (c1 > NCHUNK) c1 = NCHUNK; if (c0 > NCHUNK) c0 = NCHUNK;
  float4 z = make_float4(0.f,0.f,0.f,0.f);
  float4 sNa=z, sNb=z, sDa=z, sDb=z;
  for (int c = c0; c < c1; c++) {
    size_t o = (size_t)c*2*J_ + (size_t)kg*J_ + j;
    sNa = f4add(sNa, g_pnA[o]); sNb = f4add(sNb, g_pnB[o]);
    sDa = f4add(sDa, g_pdA[o]); sDb = f4add(sDb, g_pdB[o]);
  }
  __shared__ float4 rNa[16][16], rNb[16][16], rDa[16][16], rDb[16][16];
  rNa[slice][t & 15] = sNa; rNb[slice][t & 15] = sNb;
  rDa[slice][t & 15] = sDa; rDb[slice][t & 15] = sDb;
  __syncthreads();
  if (t < 16) {
    float4 na = rNa[0][t], nb = rNb[0][t], da = rDa[0][t], db = rDb[0][t];
#pragma unroll
    for (int s = 1; s < 16; s++) {
      na = f4add(na, rNa[s][t]); nb = f4add(nb, rNb[s][t]);
      da = f4add(da, rDa[s][t]); db = f4add(db, rDb[s][t]);
    }
    int gg = blockIdx.x*16 + t;
    int kg2 = gg >> 11, j2 = gg & (J_-1);
    float4 v0 = g_Vt4[(size_t)j2*4 + kg2];       // n=0, k-group kg2
    float4 v1 = g_Vt4[(size_t)j2*4 + 2 + kg2];   // n=1
    v0.x *= sqrtf(na.x/da.x); v0.y *= sqrtf(na.y/da.y); v0.z *= sqrtf(na.z/da.z); v0.w *= sqrtf(na.w/da.w);
    v1.x *= sqrtf(nb.x/db.x); v1.y *= sqrtf(nb.y/db.y); v1.z *= sqrtf(nb.z/db.z); v1.w *= sqrtf(nb.w/db.w);
    g_Vt4[(size_t)j2*4 + kg2] = v0;
    g_Vt4[(size_t)j2*4 + 2 + kg2] = v1;
  }
}

// ---------- final: fused D-accum + solve + Y output (Xc staged in LDS) ----------
__global__ __launch_bounds__(256, 2) void k_yout(float* __restrict__ out, int cplx) {
  int i = blockIdx.x, t = threadIdx.x;
  int wv = t >> 6, lane = t & 63;
  __shared__ float4 sXc[8][256];
  __shared__ float redD[4][12];
  __shared__ float2 sW[4];

  const float4* T4 = (const float4*)g_Tt;
  float4 tt0 = T4[i*4+0], tt1 = T4[i*4+1], tt2 = T4[i*4+2], tt3 = T4[i*4+3];

  // single global Xc row load + LDS stage
  size_t xb = (size_t)i*J_ + wv*512 + lane;
  float4 xv0 = g_Xc[xb+0*64], xv1 = g_Xc[xb+1*64], xv2 = g_Xc[xb+2*64], xv3 = g_Xc[xb+3*64];
  float4 xv4 = g_Xc[xb+4*64], xv5 = g_Xc[xb+5*64], xv6 = g_Xc[xb+6*64], xv7 = g_Xc[xb+7*64];
  sXc[0][t] = xv0; sXc[1][t] = xv1; sXc[2][t] = xv2; sXc[3][t] = xv3;
  sXc[4][t] = xv4; sXc[5][t] = xv5; sXc[6][t] = xv6; sXc[7][t] = xv7;

  {
    float s0=0.f,s1=0.f,s2=0.f,s3=0.f,s4=0.f,s5=0.f,s6=0.f,s7=0.f,s8=0.f,s9=0.f,s10=0.f,s11=0.f;
#define DB(U) { int j = wv*512 + U*64 + lane; \
    const float4* Vp = g_Vt4 + (size_t)j*4; \
    float4 vt0=Vp[0], vt1=Vp[1], vt2=Vp[2], vt3=Vp[3]; \
    float rn0 = dot44(tt0,vt0)+dot44(tt1,vt1); \
    float rn1 = dot44(tt2,vt2)+dot44(tt3,vt3); \
    float a0=xv##U.x, b0=xv##U.y, a1=xv##U.z, b1=xv##U.w; \
    float e00r=a0*a0-b0*b0, e00i=2.f*a0*b0; \
    float e01r=a0*a1-b0*b1, e01i=a0*b1+a1*b0; \
    float e11r=a1*a1-b1*b1, e11i=2.f*a1*b1; \
    float inv0=frcp(rn0), inv1=frcp(rn1); \
    s0=fmaf(e00r,inv0,s0);  s1=fmaf(e00i,inv0,s1); \
    s2=fmaf(e01r,inv0,s2);  s3=fmaf(e01i,inv0,s3); \
    s4=fmaf(e11r,inv0,s4);  s5=fmaf(e11i,inv0,s5); \
    s6=fmaf(e00r,inv1,s6);  s7=fmaf(e00i,inv1,s7); \
    s8=fmaf(e01r,inv1,s8);  s9=fmaf(e01i,inv1,s9); \
    s10=fmaf(e11r,inv1,s10); s11=fmaf(e11i,inv1,s11); }
    DB(0) DB(1) DB(2) DB(3) DB(4) DB(5) DB(6) DB(7)
#undef DB
    RW(s0) RW(s1) RW(s2) RW(s3) RW(s4) RW(s5) RW(s6) RW(s7) RW(s8) RW(s9) RW(s10) RW(s11)
    if (lane == 0) {
      redD[wv][0]=s0;  redD[wv][1]=s1;  redD[wv][2]=s2;  redD[wv][3]=s3;
      redD[wv][4]=s4;  redD[wv][5]=s5;  redD[wv][6]=s6;  redD[wv][7]=s7;
      redD[wv][8]=s8;  redD[wv][9]=s9;  redD[wv][10]=s10; redD[wv][11]=s11;
    }
  }
  __syncthreads();
  if (t == 0) {
    double s_[12];
#pragma unroll
    for (int q = 0; q < 12; q++)
      s_[q] = (double)redD[0][q] + (double)redD[1][q] + (double)redD[2][q] + (double)redD[3][q];
    float2 w[4];
    solve12(i, s_, w);
    sW[0] = w[0]; sW[1] = w[1]; sW[2] = w[2]; sW[3] = w[3];
  }
  __syncthreads();
  float2 w00 = sW[0], w01 = sW[1], w10 = sW[2], w11 = sW[3];
  float2* out2 = (float2*)out;
#define YB(U) { int j = wv*512 + U*64 + lane; \
  float4 xl = sXc[U][t]; \
  float2 x0 = make_float2(xl.x, xl.y); \
  float2 x1 = make_float2(xl.z, xl.w); \
  float2 y0 = cyn(w00, w01, x0, x1); \
  float2 y1 = cyn(w10, w11, x0, x1); \
  if (cplx) { \
    out2[((size_t)i*N_ + 0)*J_ + j] = y0; \
    out2[((size_t)i*N_ + 1)*J_ + j] = y1; \
  } else { \
    out[((size_t)i*N_ + 0)*J_ + j] = y0.x; \
    out[((size_t)i*N_ + 1)*J_ + j] = y1.x; \
  } }
  YB(0) YB(1) YB(2) YB(3) YB(4) YB(5) YB(6) YB(7)
#undef YB
}

extern "C" void kernel_launch(void* const* d_in, const int* in_sizes, int n_in,
                              void* d_out, int out_size, void* d_ws, size_t ws_size,
                              hipStream_t stream) {
  const float* X  = (const float*)d_in[0];
  const float* T0 = (const float*)d_in[1];
  const float* V0 = (const float*)d_in[2];
  (void)d_ws; (void)ws_size;

  // grid covers I_*K_ = 16392 (largest init domain) — 65 blocks
  k_setup<<<(I_*K_ + 255)/256, 256, 0, stream>>>(T0, V0);
  k_transpose<<<dim3((I_ + 63)/64, J_/32), 256, 0, stream>>>(X);

  int cplx = (out_size >= 2*I_*N_*J_) ? 1 : 0;
  for (int it = 0; it < NITER; it++) {
    // it>0: k_tv solves W(it) in-block from its own D phase (prev iter's T,V), then T-update
    k_tv<<<I_, 256, 0, stream>>>(it > 0);
    k_vupd2<<<dim3(J_/256, NCHUNK), 256, 0, stream>>>();
    k_vapply2<<<2*J_/16, 256, 0, stream>>>();
  }
  k_yout<<<I_, 256, 0, stream>>>((float*)d_out, cplx);   // fused final D + solve + Y
}